// Round 2
// baseline (462.782 us; speedup 1.0000x reference)
//
#include <hip/hip_runtime.h>

#define NB 16
#define NT 16384
#define ND 256
#define NS 4
#define SLICES 16
#define TPB 1024            // tokens per block (NT / SLICES)
#define CHUNK 32
#define NITER (TPB / CHUNK) // 32

typedef float          f32x4 __attribute__((ext_vector_type(4)));
typedef short          s16x8 __attribute__((ext_vector_type(8)));
typedef unsigned short u16x4 __attribute__((ext_vector_type(4)));

__device__ __forceinline__ unsigned short f2bf(float f) {
  // round-to-nearest-even fp32 -> bf16
  unsigned int u = __float_as_uint(f);
  return (unsigned short)((u + 0x7FFFu + ((u >> 16) & 1u)) >> 16);
}

// One block = one (batch, K-slice of 1024 tokens). Fused: load fp32 rows ->
// L2-normalize -> bf16 -> in-LDS transpose to K-blocked layout -> MFMA Gram
// (UPPER TRIANGLE of 256x256 per block; Gvv symmetric) -> PLAIN predicated
// stores of the per-slice partial into Gpart[b][slice] (no atomics; the 16
// slice partials are summed in finalize). Removes 8.4M contended L2 atomics.
__global__ __launch_bounds__(512, 2) void fused_gram(
    const float* __restrict__ emb, const float* __restrict__ lab,
    float* __restrict__ Gpart, float* __restrict__ Gvy, float* __restrict__ Cnt)
{
  const int tid  = threadIdx.x;
  const int lane = tid & 63;
  const int w    = tid >> 6;           // wave 0..7
  const int b     = blockIdx.x >> 4;
  const int slice = blockIdx.x & 15;
  const int t0    = slice * TPB;

  // LDS: row-major normalized chunk (pad 260 to break bank patterns),
  // K-blocked bf16 tile [tg(4)][d(256)][8 tokens], speaker ids, counts.
  __shared__ __align__(16) unsigned short rm[CHUNK * 260];     // 16.6 KB
  __shared__ __align__(16) unsigned short blkT[4 * 256 * 8];   // 16 KB
  __shared__ int   spk[TPB];                                   // 4 KB
  __shared__ float cnt_lds[NS];

  if (tid < NS) cnt_lds[tid] = 0.0f;
  __syncthreads();

  // decode one-hot speakers for the block's 1024 tokens, count per speaker
  {
    const f32x4* lv = (const f32x4*)(lab + ((size_t)b * NT + t0) * NS);
    for (int i = tid; i < TPB; i += 512) {
      f32x4 y = lv[i];
      int s = (int)(y.y + 2.0f * y.z + 3.0f * y.w + 0.5f);
      spk[i] = s;
      atomicAdd(&cnt_lds[s], 1.0f);
    }
  }

  const float* embB = emb + ((size_t)b * NT + t0) * ND;
  const int wr = w >> 2, wc = w & 3;   // wave tile: rows wr*128, cols wc*64
  // waves 4,5 (rows 128..255 x cols 0..127) are entirely below the diagonal:
  // their Gram output is redundant under symmetry -> skip their MFMA phase.
  const bool live = (w != 4) && (w != 5);

  f32x4 acc[8][4];
  #pragma unroll
  for (int i = 0; i < 8; ++i)
    #pragma unroll
    for (int j = 0; j < 4; ++j) acc[i][j] = (f32x4){0.f, 0.f, 0.f, 0.f};

  // prefetch chunk 0: each wave owns 4 tokens, lane holds cols 4l..4l+3
  f32x4 pf[4];
  #pragma unroll
  for (int j = 0; j < 4; ++j)
    pf[j] = *(const f32x4*)(embB + (size_t)(w * 4 + j) * ND + 4 * lane);

  float rgvy0 = 0.f, rgvy1 = 0.f, rgvy2 = 0.f, rgvy3 = 0.f;

  for (int it = 0; it < NITER; ++it) {
    // ---- phase N: normalize chunk `it`, write row-major LDS ----
    #pragma unroll
    for (int j = 0; j < 4; ++j) {
      f32x4 v = pf[j];
      float ss = v.x * v.x + v.y * v.y + v.z * v.z + v.w * v.w;
      #pragma unroll
      for (int off = 32; off; off >>= 1) ss += __shfl_xor(ss, off);
      float sc = 1.0f / fmaxf(sqrtf(ss), 1e-12f);
      u16x4 st;
      st.x = f2bf(v.x * sc); st.y = f2bf(v.y * sc);
      st.z = f2bf(v.z * sc); st.w = f2bf(v.w * sc);
      *(u16x4*)&rm[(w * 4 + j) * 260 + 4 * lane] = st;
    }
    // issue next chunk's global loads (overlap with transpose + MFMA below)
    if (it + 1 < NITER) {
      const float* p = embB + (size_t)((it + 1) * CHUNK + w * 4) * ND + 4 * lane;
      #pragma unroll
      for (int j = 0; j < 4; ++j) pf[j] = *(const f32x4*)(p + j * ND);
    }
    __syncthreads();

    // ---- phase T: 8x8 micro-transpose to K-blocked layout + Gvy accum ----
    #pragma unroll
    for (int pp = 0; pp < 2; ++pp) {
      int p  = tid + pp * 512;       // p = tg*256 + c ; c fixed per thread
      int tg = p >> 8, c = p & 255;
      int tb = tg * 8;
      s16x8 v8;
      #pragma unroll
      for (int s8 = 0; s8 < 8; ++s8) {
        unsigned short u = rm[(tb + s8) * 260 + c];
        v8[s8] = (short)u;
        float fv = __uint_as_float((unsigned int)u << 16);
        int sp = spk[it * CHUNK + tb + s8];
        rgvy0 += (sp == 0) ? fv : 0.0f;
        rgvy1 += (sp == 1) ? fv : 0.0f;
        rgvy2 += (sp == 2) ? fv : 0.0f;
        rgvy3 += (sp == 3) ? fv : 0.0f;
      }
      *(s16x8*)&blkT[p * 8] = v8;    // 16B store, uniform bank coverage
    }
    __syncthreads();

    // ---- phase M: Gram MFMA on chunk `it` (K=32 per mfma) ----
    if (live) {
      const short* bp = (const short*)blkT;
      const int quad = lane >> 4, m16 = lane & 15;
      s16x8 afr[8];
      #pragma unroll
      for (int mi = 0; mi < 8; ++mi)
        afr[mi] = *(const s16x8*)(bp + (((quad << 8) + wr * 128 + mi * 16 + m16) << 3));
      #pragma unroll
      for (int mj = 0; mj < 4; ++mj) {
        s16x8 bfr = *(const s16x8*)(bp + (((quad << 8) + wc * 64 + mj * 16 + m16) << 3));
        #pragma unroll
        for (int mi = 0; mi < 8; ++mi)
          acc[mi][mj] = __builtin_amdgcn_mfma_f32_16x16x32_bf16(afr[mi], bfr, acc[mi][mj], 0, 0, 0);
      }
    }
    // no barrier needed: next phase N writes rm (not blkT); next phase T is
    // behind next iteration's first __syncthreads.
  }

  // ---- epilogue: PLAIN predicated stores of this slice's upper triangle ----
  if (live) {
    float* Gb = Gpart + (size_t)blockIdx.x * (ND * ND);  // blockIdx = b*16+slice
    const int quad = lane >> 4, m16 = lane & 15;
    #pragma unroll
    for (int mi = 0; mi < 8; ++mi)
      #pragma unroll
      for (int mj = 0; mj < 4; ++mj)
        #pragma unroll
        for (int r = 0; r < 4; ++r) {
          int row = wr * 128 + mi * 16 + quad * 4 + r;   // C/D: row = quad*4+reg
          int col = wc * 64 + mj * 16 + m16;             //      col = lane&15
          if (row <= col)
            Gb[row * ND + col] = acc[mi][mj][r];
        }
  }
  {
    int c = tid & 255;
    float* gy = Gvy + (size_t)b * (NS * ND);
    atomicAdd(&gy[0 * ND + c], rgvy0);
    atomicAdd(&gy[1 * ND + c], rgvy1);
    atomicAdd(&gy[2 * ND + c], rgvy2);
    atomicAdd(&gy[3 * ND + c], rgvy3);
  }
  __syncthreads();
  if (tid < NS) atomicAdd(&Cnt[b * NS + tid], cnt_lds[tid]);
}

// Per block: (b, seg of 16 rows). Sum the 16 slice partials elementwise
// (predicated: only col >= row was ever written; below-diag is poison and
// must never be loaded), then accumulate w*s^2 with w = 2 above diag, 1 on
// diag, 0 below. seg==0 also folds in the Gvy and Cnt terms.
// loss = sum_b [ sum_upper w*Gvv^2 - 2 sum Gvy^2 + sum Cnt^2 ] / (T*T*B)
__global__ void finalize_kernel(const float* __restrict__ Gpart,
                                const float* __restrict__ Gvy,
                                const float* __restrict__ Cnt,
                                float* __restrict__ out)
{
  const int b = blockIdx.x >> 4, seg = blockIdx.x & 15;
  const int tid = threadIdx.x;         // 256: one column per thread
  const int r0 = seg * 16;

  float s16[16];
  #pragma unroll
  for (int r = 0; r < 16; ++r) s16[r] = 0.f;

  for (int sl = 0; sl < SLICES; ++sl) {
    const float* G = Gpart + (size_t)(b * SLICES + sl) * (ND * ND);
    #pragma unroll
    for (int r = 0; r < 16; ++r) {
      int row = r0 + r;
      if (tid >= row) s16[r] += G[row * ND + tid];   // exec-masked load
    }
  }

  float local = 0.f;
  #pragma unroll
  for (int r = 0; r < 16; ++r) {
    int row = r0 + r;
    float wgt = (tid > row) ? 2.0f : ((tid == row) ? 1.0f : 0.0f);
    local = fmaf(wgt * s16[r], s16[r], local);       // below-diag: 0*0
  }

  if (seg == 0) {
    const float* gy = Gvy + (size_t)b * (NS * ND);
    for (int i = tid; i < NS * ND; i += 256) { float v = gy[i]; local = fmaf(-2.f * v, v, local); }
    if (tid < NS) { float c = Cnt[b * NS + tid]; local = fmaf(c, c, local); }
  }
  #pragma unroll
  for (int off = 32; off; off >>= 1) local += __shfl_xor(local, off);
  __shared__ float wsum[4];
  if ((tid & 63) == 0) wsum[tid >> 6] = local;
  __syncthreads();
  if (tid == 0) {
    float s = wsum[0] + wsum[1] + wsum[2] + wsum[3];
    // T*T*B = 2^32, exact in fp32
    atomicAdd(out, s * (1.0f / 4294967296.0f));
  }
}

extern "C" void kernel_launch(void* const* d_in, const int* in_sizes, int n_in,
                              void* d_out, int out_size, void* d_ws, size_t ws_size,
                              hipStream_t stream) {
  const float* emb = (const float*)d_in[0];  // [16,16384,256] fp32
  const float* lab = (const float*)d_in[1];  // [16,16384,4] fp32 one-hot
  float* out = (float*)d_out;

  // ws layout: [Gvy: 16*4*256 f32][Cnt: 64 f32][pad][Gpart: 16*16*65536 f32 = 64 MB]
  float* Gvy   = (float*)d_ws;
  float* Cnt   = Gvy + (size_t)NB * NS * ND;           // 16384
  float* Gpart = (float*)d_ws + 32768;                 // 128 KB offset, aligned

  // only Gvy + Cnt need zeroing (Gpart upper-tri is fully overwritten;
  // below-diag poison is never loaded)
  size_t zbytes = ((size_t)NB * NS * ND + NB * NS) * sizeof(float);
  hipMemsetAsync(d_ws, 0, zbytes, stream);
  hipMemsetAsync(d_out, 0, sizeof(float), stream);

  fused_gram<<<dim3(NB * SLICES), dim3(512), 0, stream>>>(emb, lab, Gpart, Gvy, Cnt);
  finalize_kernel<<<dim3(NB * SLICES), dim3(256), 0, stream>>>(Gpart, Gvy, Cnt, out);
}

// Round 3
// 381.249 us; speedup vs baseline: 1.2139x; 1.2139x over previous
//
#include <hip/hip_runtime.h>

#define NB 16
#define NT 16384
#define ND 256
#define NS 4
#define SLICES 16
#define TPB 1024            // tokens per block (NT / SLICES)
#define CHUNK 32
#define NITER (TPB / CHUNK) // 32

typedef float          f32x4 __attribute__((ext_vector_type(4)));
typedef short          s16x8 __attribute__((ext_vector_type(8)));
typedef unsigned short u16x4 __attribute__((ext_vector_type(4)));

__device__ __forceinline__ unsigned short f2bf(float f) {
  // round-to-nearest-even fp32 -> bf16
  unsigned int u = __float_as_uint(f);
  return (unsigned short)((u + 0x7FFFu + ((u >> 16) & 1u)) >> 16);
}

// One block = one (batch, K-slice of 1024 tokens). Fused: load fp32 rows ->
// L2-normalize -> bf16 -> in-LDS transpose to K-blocked layout -> MFMA Gram
// (UPPER TRIANGLE of 256x256 per block; Gvv symmetric) -> PLAIN predicated
// stores of the per-slice partial into Gpart[b][slice] (no atomics; the 16
// slice partials are summed in finalize).
__global__ __launch_bounds__(512, 2) void fused_gram(
    const float* __restrict__ emb, const float* __restrict__ lab,
    float* __restrict__ Gpart, float* __restrict__ Gvy, float* __restrict__ Cnt)
{
  const int tid  = threadIdx.x;
  const int lane = tid & 63;
  const int w    = tid >> 6;           // wave 0..7
  const int b     = blockIdx.x >> 4;
  const int slice = blockIdx.x & 15;
  const int t0    = slice * TPB;

  // LDS: row-major normalized chunk (pad 260 to break bank patterns),
  // K-blocked bf16 tile [tg(4)][d(256)][8 tokens], speaker ids, counts.
  __shared__ __align__(16) unsigned short rm[CHUNK * 260];     // 16.6 KB
  __shared__ __align__(16) unsigned short blkT[4 * 256 * 8];   // 16 KB
  __shared__ int   spk[TPB];                                   // 4 KB
  __shared__ float cnt_lds[NS];

  if (tid < NS) cnt_lds[tid] = 0.0f;
  __syncthreads();

  // decode one-hot speakers for the block's 1024 tokens, count per speaker
  {
    const f32x4* lv = (const f32x4*)(lab + ((size_t)b * NT + t0) * NS);
    for (int i = tid; i < TPB; i += 512) {
      f32x4 y = lv[i];
      int s = (int)(y.y + 2.0f * y.z + 3.0f * y.w + 0.5f);
      spk[i] = s;
      atomicAdd(&cnt_lds[s], 1.0f);
    }
  }

  const float* embB = emb + ((size_t)b * NT + t0) * ND;
  const int wr = w >> 2, wc = w & 3;   // wave tile: rows wr*128, cols wc*64
  // waves 4,5 (rows 128..255 x cols 0..127) are entirely below the diagonal:
  // their Gram output is redundant under symmetry -> skip their MFMA phase.
  const bool live = (w != 4) && (w != 5);

  f32x4 acc[8][4];
  #pragma unroll
  for (int i = 0; i < 8; ++i)
    #pragma unroll
    for (int j = 0; j < 4; ++j) acc[i][j] = (f32x4){0.f, 0.f, 0.f, 0.f};

  // prefetch chunk 0: each wave owns 4 tokens, lane holds cols 4l..4l+3
  f32x4 pf[4];
  #pragma unroll
  for (int j = 0; j < 4; ++j)
    pf[j] = *(const f32x4*)(embB + (size_t)(w * 4 + j) * ND + 4 * lane);

  float rgvy0 = 0.f, rgvy1 = 0.f, rgvy2 = 0.f, rgvy3 = 0.f;

  for (int it = 0; it < NITER; ++it) {
    // ---- phase N: normalize chunk `it`, write row-major LDS ----
    #pragma unroll
    for (int j = 0; j < 4; ++j) {
      f32x4 v = pf[j];
      float ss = v.x * v.x + v.y * v.y + v.z * v.z + v.w * v.w;
      #pragma unroll
      for (int off = 32; off; off >>= 1) ss += __shfl_xor(ss, off);
      float sc = 1.0f / fmaxf(sqrtf(ss), 1e-12f);
      u16x4 st;
      st.x = f2bf(v.x * sc); st.y = f2bf(v.y * sc);
      st.z = f2bf(v.z * sc); st.w = f2bf(v.w * sc);
      *(u16x4*)&rm[(w * 4 + j) * 260 + 4 * lane] = st;
    }
    // issue next chunk's global loads (overlap with transpose + MFMA below)
    if (it + 1 < NITER) {
      const float* p = embB + (size_t)((it + 1) * CHUNK + w * 4) * ND + 4 * lane;
      #pragma unroll
      for (int j = 0; j < 4; ++j) pf[j] = *(const f32x4*)(p + j * ND);
    }
    __syncthreads();

    // ---- phase T: 8x8 micro-transpose to K-blocked layout + Gvy accum ----
    #pragma unroll
    for (int pp = 0; pp < 2; ++pp) {
      int p  = tid + pp * 512;       // p = tg*256 + c ; c fixed per thread
      int tg = p >> 8, c = p & 255;
      int tb = tg * 8;
      s16x8 v8;
      #pragma unroll
      for (int s8 = 0; s8 < 8; ++s8) {
        unsigned short u = rm[(tb + s8) * 260 + c];
        v8[s8] = (short)u;
        float fv = __uint_as_float((unsigned int)u << 16);
        int sp = spk[it * CHUNK + tb + s8];
        rgvy0 += (sp == 0) ? fv : 0.0f;
        rgvy1 += (sp == 1) ? fv : 0.0f;
        rgvy2 += (sp == 2) ? fv : 0.0f;
        rgvy3 += (sp == 3) ? fv : 0.0f;
      }
      *(s16x8*)&blkT[p * 8] = v8;    // 16B store, uniform bank coverage
    }
    __syncthreads();

    // ---- phase M: Gram MFMA on chunk `it` (K=32 per mfma) ----
    if (live) {
      const short* bp = (const short*)blkT;
      const int quad = lane >> 4, m16 = lane & 15;
      s16x8 afr[8];
      #pragma unroll
      for (int mi = 0; mi < 8; ++mi)
        afr[mi] = *(const s16x8*)(bp + (((quad << 8) + wr * 128 + mi * 16 + m16) << 3));
      #pragma unroll
      for (int mj = 0; mj < 4; ++mj) {
        s16x8 bfr = *(const s16x8*)(bp + (((quad << 8) + wc * 64 + mj * 16 + m16) << 3));
        #pragma unroll
        for (int mi = 0; mi < 8; ++mi)
          acc[mi][mj] = __builtin_amdgcn_mfma_f32_16x16x32_bf16(afr[mi], bfr, acc[mi][mj], 0, 0, 0);
      }
    }
    // no barrier needed: next phase N writes rm (not blkT); next phase T is
    // behind next iteration's first __syncthreads.
  }

  // ---- epilogue: PLAIN predicated stores of this slice's upper triangle ----
  if (live) {
    float* Gb = Gpart + (size_t)blockIdx.x * (ND * ND);  // blockIdx = b*16+slice
    const int quad = lane >> 4, m16 = lane & 15;
    #pragma unroll
    for (int mi = 0; mi < 8; ++mi)
      #pragma unroll
      for (int mj = 0; mj < 4; ++mj)
        #pragma unroll
        for (int r = 0; r < 4; ++r) {
          int row = wr * 128 + mi * 16 + quad * 4 + r;   // C/D: row = quad*4+reg
          int col = wc * 64 + mj * 16 + m16;             //      col = lane&15
          if (row <= col)
            Gb[row * ND + col] = acc[mi][mj][r];
        }
  }
  {
    int c = tid & 255;
    float* gy = Gvy + (size_t)b * (NS * ND);
    atomicAdd(&gy[0 * ND + c], rgvy0);
    atomicAdd(&gy[1 * ND + c], rgvy1);
    atomicAdd(&gy[2 * ND + c], rgvy2);
    atomicAdd(&gy[3 * ND + c], rgvy3);
  }
  __syncthreads();
  if (tid < NS) atomicAdd(&Cnt[b * NS + tid], cnt_lds[tid]);
}

// Per block: (b, seg of 16 rows r0..r0+15). Thread owns column c = r0+tid
// (cols < r0 are below-diag for every row in the segment -> skipped; read
// traffic ~34 MB instead of 64 MB, still coalesced). Loads are
// UNCONDITIONAL; below-diag poison is discarded with a bitwise select
// (never enters FP math) so the load pipeline has full ILP — no per-load
// exec-mask churn (the R2 bug: divergent-predicated loads serialized at
// ~600 cyc each with 1 wave/SIMD => ~64 us).
// loss = sum_b [ sum_upper w*Gvv^2 - 2 sum Gvy^2 + sum Cnt^2 ] / (T*T*B)
__global__ void finalize_kernel(const float* __restrict__ Gpart,
                                const float* __restrict__ Gvy,
                                const float* __restrict__ Cnt,
                                float* __restrict__ out)
{
  const int b = blockIdx.x >> 4, seg = blockIdx.x & 15;
  const int tid = threadIdx.x;         // 256
  const int r0 = seg * 16;
  const int c  = r0 + tid;             // column this thread owns
  float local = 0.f;

  if (c < ND) {                        // loop-invariant guard, one exec set
    float s16[16];
    #pragma unroll
    for (int r = 0; r < 16; ++r) s16[r] = 0.f;

    for (int sl = 0; sl < SLICES; ++sl) {
      const float* G = Gpart + (size_t)(b * SLICES + sl) * (ND * ND) + c;
      #pragma unroll
      for (int r = 0; r < 16; ++r) {
        float v = G[(size_t)(r0 + r) * ND];      // unconditional load
        s16[r] += (tid >= r) ? v : 0.0f;         // select; poison discarded
      }
    }

    #pragma unroll
    for (int r = 0; r < 16; ++r) {
      float wgt = (tid > r) ? 2.0f : ((tid == r) ? 1.0f : 0.0f);
      local = fmaf(wgt * s16[r], s16[r], local); // below-diag: wgt*0*0
    }
  }

  if (seg == 0) {
    const float* gy = Gvy + (size_t)b * (NS * ND);
    for (int i = tid; i < NS * ND; i += 256) { float v = gy[i]; local = fmaf(-2.f * v, v, local); }
    if (tid < NS) { float cc = Cnt[b * NS + tid]; local = fmaf(cc, cc, local); }
  }
  #pragma unroll
  for (int off = 32; off; off >>= 1) local += __shfl_xor(local, off);
  __shared__ float wsum[4];
  if ((tid & 63) == 0) wsum[tid >> 6] = local;
  __syncthreads();
  if (tid == 0) {
    float s = wsum[0] + wsum[1] + wsum[2] + wsum[3];
    // T*T*B = 2^32, exact in fp32
    atomicAdd(out, s * (1.0f / 4294967296.0f));
  }
}

extern "C" void kernel_launch(void* const* d_in, const int* in_sizes, int n_in,
                              void* d_out, int out_size, void* d_ws, size_t ws_size,
                              hipStream_t stream) {
  const float* emb = (const float*)d_in[0];  // [16,16384,256] fp32
  const float* lab = (const float*)d_in[1];  // [16,16384,4] fp32 one-hot
  float* out = (float*)d_out;

  // ws layout: [Gvy: 16*4*256 f32][Cnt: 64 f32][pad][Gpart: 16*16*65536 f32 = 64 MB]
  float* Gvy   = (float*)d_ws;
  float* Cnt   = Gvy + (size_t)NB * NS * ND;           // 16384
  float* Gpart = (float*)d_ws + 32768;                 // 128 KB offset, aligned

  // only Gvy + Cnt need zeroing (Gpart upper-tri is fully overwritten;
  // below-diag poison is never used)
  size_t zbytes = ((size_t)NB * NS * ND + NB * NS) * sizeof(float);
  hipMemsetAsync(d_ws, 0, zbytes, stream);
  hipMemsetAsync(d_out, 0, sizeof(float), stream);

  fused_gram<<<dim3(NB * SLICES), dim3(512), 0, stream>>>(emb, lab, Gpart, Gvy, Cnt);
  finalize_kernel<<<dim3(NB * SLICES), dim3(256), 0, stream>>>(Gpart, Gvy, Cnt, out);
}